// Round 8
// baseline (60.042 us; speedup 1.0000x reference)
//
#include <hip/hip_runtime.h>

// ---------------------------------------------------------------------------
// LeNet5-KAN on MI355X.  R8: single fused kernel conv1->pool->conv2->pool->fc.
// Block = 2 images, 384 thr = 6 waves (0-2 img0, 3-5 img1). MFMA f16/f32;
// avg-pool folded into conv weights (stride-2 conv6x6); fc chain in-block
// with f32 weights from L2; out written directly.
//
// GEMM view per conv:  out[p][o] = sum_K feat16[elem(p,tap)][k] * W[tap,k][o]
//   K = taps(36) x kpad(16): k0..7 = cubic B-spline bases, k8 = relu, rest 0.
//   A-frag: lane&15 = out px, lane>>4 = k-group (16B ds_read_b128)
//   B-frag: lane&15 = o,     lane>>4 = same k-group (16B global load, L2)
//   C     : col = lane&15 (o), row = (lane>>4)*4 + reg
// feat LDS chunks (16B) XOR-swizzled: ch ^= (ch>>3)&7.
// ---------------------------------------------------------------------------

typedef _Float16 f16;
typedef f16 f16x8 __attribute__((ext_vector_type(8)));
typedef float f32x4 __attribute__((ext_vector_type(4)));

#define ONE_SIXTH 0.16666666666666666f

__device__ __forceinline__ void spline9(float v, float* __restrict__ f) {
    float u  = 2.5f * v + 5.5f;
    bool valid = (u >= 0.0f) && (u < 11.0f);
    float fi = floorf(u);
    int   i  = (int)fi;
    float w  = u - fi;
    float omw = 1.0f - w;
    float w2 = w * w, w3 = w2 * w;
    float c0 = omw * omw * omw * ONE_SIXTH;
    float c1 = (3.0f * w3 - 6.0f * w2 + 4.0f) * ONE_SIXTH;
    float c2 = (-3.0f * w3 + 3.0f * w2 + 3.0f * w + 1.0f) * ONE_SIXTH;
    float c3 = w3 * ONE_SIXTH;
    int j0 = i - 3;
#pragma unroll
    for (int j = 0; j < 8; ++j) {
        int d = j - j0;
        float val = (d == 0) ? c0 : (d == 1) ? c1 : (d == 2) ? c2 : (d == 3) ? c3 : 0.0f;
        f[j] = valid ? val : 0.0f;
    }
    f[8] = fmaxf(v, 0.0f);
}

// two 16B chunks: c0 = bases[0..7] as f16, c1 = {relu, 0 x7}
__device__ __forceinline__ void spline_chunks(float v, uint4& u0, uint4& u1) {
    float f[9];
    spline9(v, f);
    union { f16 h[8]; uint4 u; } a, b;
#pragma unroll
    for (int j = 0; j < 8; ++j) a.h[j] = (f16)f[j];
    b.u.x = 0u; b.u.y = 0u; b.u.z = 0u; b.u.w = 0u;
    b.h[0] = (f16)f[8];
    u0 = a.u; u1 = b.u;
}

// ---------------------------------------------------------------------------
// K0: build pooled-conv weights, f16.
// W1g[(tap*16 + o)*16 + k], tap<36, o<16 (6 valid), k<16 (9 valid)
// W2g[((c*36 + tap)*16 + o)*16 + k], c<6
// w'[ey][ex] = 0.25 * sum_{a,b in {0,1}, 0<=ey-a<5, 0<=ex-b<5} w[ey-a][ex-b]
// ---------------------------------------------------------------------------
__global__ __launch_bounds__(256) void k_prep(
    const float* __restrict__ c1_bw, const float* __restrict__ c1_sw,
    const float* __restrict__ c1_sc,
    const float* __restrict__ c2_bw, const float* __restrict__ c2_sw,
    const float* __restrict__ c2_sc,
    f16* __restrict__ W1g, f16* __restrict__ W2g)
{
    int t = blockIdx.x * 256 + threadIdx.x;
    if (t < 9216) {
        int tap = t >> 8, r = t & 255;
        int o = r >> 4, k = r & 15;
        float val = 0.0f;
        if (o < 6 && k < 9) {
            int ey = tap / 6, ex = tap - 6 * ey;
            float s = 0.0f;
            for (int a = 0; a < 2; ++a) {
                for (int b = 0; b < 2; ++b) {
                    int dy = ey - a, dx = ex - b;
                    if (dy >= 0 && dy < 5 && dx >= 0 && dx < 5) {
                        int idx = o * 25 + dy * 5 + dx;
                        s += (k == 8) ? c1_bw[idx] : c1_sw[idx * 8 + k] * c1_sc[idx];
                    }
                }
            }
            val = 0.25f * s;
        }
        W1g[t] = (f16)val;
    }
    if (t < 55296) {
        int c = t / 9216, r = t - c * 9216;
        int tap = r >> 8, rr = r & 255;
        int o = rr >> 4, k = rr & 15;
        float val = 0.0f;
        if (k < 9) {
            int ey = tap / 6, ex = tap - 6 * ey;
            float s = 0.0f;
            for (int a = 0; a < 2; ++a) {
                for (int b = 0; b < 2; ++b) {
                    int dy = ey - a, dx = ex - b;
                    if (dy >= 0 && dy < 5 && dx >= 0 && dx < 5) {
                        int idx = o * 150 + c * 25 + dy * 5 + dx;
                        s += (k == 8) ? c2_bw[idx] : c2_sw[idx * 8 + k] * c2_sc[idx];
                    }
                }
            }
            val = 0.25f * s;
        }
        W2g[t] = (f16)val;
    }
}

// ---------------------------------------------------------------------------
// K1: fully fused. Block = 2 images, 384 thr = 6 waves.
// A: spline-stage x.  B: conv1 MFMA -> h1 in LDS.  C: spline-stage h1.
// D: conv2 MFMA (K 3-way split, 2 acc chains) -> reduce -> h2 in LDS.
// E: fc1(relu)->fc2(relu)->fc3 -> out.
// ---------------------------------------------------------------------------
__global__ __launch_bounds__(384, 2) void k_fused(
    const float* __restrict__ x, const f16* __restrict__ W1g,
    const f16* __restrict__ W2g,
    const float* __restrict__ w1, const float* __restrict__ b1,
    const float* __restrict__ w2, const float* __restrict__ b2,
    const float* __restrict__ w3, const float* __restrict__ b3,
    float* __restrict__ out)
{
    __shared__ __align__(16) uint4  feat[2][1728];
    __shared__ __align__(16) float  h1l[2][864];
    __shared__ __align__(16) float4 rbuf[2][2][64];
    __shared__ __align__(16) float  h2l[2][256];
    __shared__ __align__(16) float  a1[2][120];
    __shared__ __align__(16) float  a2[2][84];

    const int i0 = blockIdx.x * 2;
    const int tid = threadIdx.x;
    const int lane = tid & 63, wv = tid >> 6;
    const int im = wv >= 3 ? 1 : 0;          // wave's image
    const int wvv = wv - 3 * im;             // wave index within image (0..2)
    const int ln15 = lane & 15, g = lane >> 4;
    const int gh = g & 1, gt = g >> 1;

    // ---- Phase A: stage feat(x) for both images ----
    for (int e = tid; e < 1568; e += 384) {
        int m = e >= 784, r = e - 784 * m;
        uint4 u0, u1;
        spline_chunks(x[(i0 + m) * 784 + r], u0, u1);
        int ch = r * 2;
        int q = (ch >> 3) & 7;
        feat[m][ch ^ q] = u0;
        feat[m][(ch + 1) ^ q] = u1;
    }
    __syncthreads();

    // ---- Phase B: conv1 ----
    {
        int ebase[3];
#pragma unroll
        for (int t = 0; t < 3; ++t) {
            int p = (wvv * 3 + t) * 16 + ln15;
            int py = p / 12, px = p - py * 12;
            ebase[t] = py * 56 + px * 2;            // (2py)*28 + 2px
        }
        const f16* bptr = W1g + (gt * 16 + ln15) * 16 + gh * 8;
        f16x8 bfrag = *(const f16x8*)bptr;
        f32x4 acc[3] = {{0,0,0,0},{0,0,0,0},{0,0,0,0}};

        for (int kc = 0; kc < 18; ++kc) {
            int tap = kc * 2 + gt;
            int ey = (tap * 171) >> 10, ex = tap - ey * 6;
            int eoff = ey * 28 + ex;
            f16x8 bcur = bfrag;
            bptr += 512;
            bfrag = *(const f16x8*)bptr;            // overreads into W2g: safe
#pragma unroll
            for (int t = 0; t < 3; ++t) {
                int ch = (ebase[t] + eoff) * 2 + gh;
                ch ^= (ch >> 3) & 7;
                f16x8 afrag = *(const f16x8*)(&feat[im][ch]);
                acc[t] = __builtin_amdgcn_mfma_f32_16x16x32_f16(afrag, bcur, acc[t], 0, 0, 0);
            }
        }
        if (ln15 < 6) {
#pragma unroll
            for (int t = 0; t < 3; ++t) {
                int p0 = (wvv * 3 + t) * 16 + g * 4;    // row = g*4 + reg
                *(float4*)&h1l[im][ln15 * 144 + p0] =
                    make_float4(acc[t][0], acc[t][1], acc[t][2], acc[t][3]);
            }
        }
    }
    __syncthreads();    // feat reads done + h1l visible

    // ---- Phase C: stage feat(h1) ----
    for (int e = tid; e < 1728; e += 384) {
        int m = e >= 864, r = e - 864 * m;
        uint4 u0, u1;
        spline_chunks(h1l[m][r], u0, u1);
        int ch = r * 2;
        int q = (ch >> 3) & 7;
        feat[m][ch ^ q] = u0;
        feat[m][(ch + 1) ^ q] = u1;
    }
    __syncthreads();

    // ---- Phase D: conv2, K split over 3 waves, 2 acc chains ----
    {
        const int py = ln15 >> 2, px = ln15 & 3;
        const int epx = py * 24 + px * 2;           // (2py)*12 + 2px
        const int kk0 = wvv * 36;
        const f16* bptr = W2g + ((kk0 * 2 + gt) * 16 + ln15) * 16 + gh * 8;
        f16x8 bfrag = *(const f16x8*)bptr;
        f32x4 accA = {0, 0, 0, 0}, accB = {0, 0, 0, 0};

        for (int i = 0; i < 36; i += 2) {
#pragma unroll
            for (int s = 0; s < 2; ++s) {
                int kk = kk0 + i + s;
                int c = kk / 18, tk = kk - c * 18;
                int tap = tk * 2 + gt;
                int ey = (tap * 171) >> 10, ex = tap - ey * 6;
                f16x8 bcur = bfrag;
                bptr += 512;
                bfrag = *(const f16x8*)bptr;        // overread past W2g: padded ws
                int elem = c * 144 + epx + ey * 12 + ex;
                int ch = elem * 2 + gh;
                ch ^= (ch >> 3) & 7;
                f16x8 afrag = *(const f16x8*)(&feat[im][ch]);
                if (s == 0)
                    accA = __builtin_amdgcn_mfma_f32_16x16x32_f16(afrag, bcur, accA, 0, 0, 0);
                else
                    accB = __builtin_amdgcn_mfma_f32_16x16x32_f16(afrag, bcur, accB, 0, 0, 0);
            }
        }
        f32x4 acc = accA + accB;

        if (wvv) rbuf[im][wvv - 1][lane] = make_float4(acc[0], acc[1], acc[2], acc[3]);
        __syncthreads();
        if (wvv == 0) {
            float4 r0 = rbuf[im][0][lane], r1 = rbuf[im][1][lane];
            *(float4*)&h2l[im][ln15 * 16 + g * 4] =
                make_float4(acc[0] + r0.x + r1.x, acc[1] + r0.y + r1.y,
                            acc[2] + r0.z + r1.z, acc[3] + r0.w + r1.w);
        }
    }
    __syncthreads();

    // ---- Phase E: fc chain ----
    if (tid < 240) {                 // 2 img x 120 outs
        const int m = tid >= 120, o = tid - 120 * m;
        const float* w = w1 + o * 256;
        float s = 0.0f;
#pragma unroll 8
        for (int k = 0; k < 64; ++k) {
            float4 wv4 = ((const float4*)w)[k];
            float4 xv = *(const float4*)(&h2l[m][k * 4]);
            s += wv4.x * xv.x + wv4.y * xv.y + wv4.z * xv.z + wv4.w * xv.w;
        }
        a1[m][o] = fmaxf(s + b1[o], 0.0f);
    }
    __syncthreads();

    if (tid < 168) {                 // 2 img x 84 outs
        const int m = tid >= 84, o = tid - 84 * m;
        const float* w = w2 + o * 120;
        float s = 0.0f;
#pragma unroll
        for (int k = 0; k < 30; ++k) {
            float4 wv4 = ((const float4*)w)[k];
            float4 xv = *(const float4*)(&a1[m][k * 4]);
            s += wv4.x * xv.x + wv4.y * xv.y + wv4.z * xv.z + wv4.w * xv.w;
        }
        a2[m][o] = fmaxf(s + b2[o], 0.0f);
    }
    __syncthreads();

    if (tid < 124) {                 // 2 img x 62 outs
        const int m = tid >= 62, o = tid - 62 * m;
        const float* w = w3 + o * 84;
        float s = 0.0f;
#pragma unroll
        for (int k = 0; k < 21; ++k) {
            float4 wv4 = ((const float4*)w)[k];
            float4 xv = *(const float4*)(&a2[m][k * 4]);
            s += wv4.x * xv.x + wv4.y * xv.y + wv4.z * xv.z + wv4.w * xv.w;
        }
        out[(i0 + m) * 62 + o] = s + b3[o];
    }
}

// ---------------------------------------------------------------------------
extern "C" void kernel_launch(void* const* d_in, const int* in_sizes, int n_in,
                              void* d_out, int out_size, void* d_ws, size_t ws_size,
                              hipStream_t stream)
{
    (void)in_sizes; (void)n_in; (void)out_size; (void)ws_size;
    const float* x      = (const float*)d_in[0];
    const float* c1_bw  = (const float*)d_in[1];
    const float* c1_sw  = (const float*)d_in[2];
    const float* c1_sc  = (const float*)d_in[3];
    const float* c2_bw  = (const float*)d_in[4];
    const float* c2_sw  = (const float*)d_in[5];
    const float* c2_sc  = (const float*)d_in[6];
    const float* fc1_w  = (const float*)d_in[7];
    const float* fc1_b  = (const float*)d_in[8];
    const float* fc2_w  = (const float*)d_in[9];
    const float* fc2_b  = (const float*)d_in[10];
    const float* fc3_w  = (const float*)d_in[11];
    const float* fc3_b  = (const float*)d_in[12];
    float* out = (float*)d_out;

    char* wsb = (char*)d_ws;
    f16* W1g = (f16*)(wsb);                    //  9216 f16 = 18432 B
    f16* W2g = (f16*)(wsb + 18432);            // 55296 f16 = 110592 B (+pad after)

    hipLaunchKernelGGL(k_prep, dim3(256), dim3(256), 0, stream,
                       c1_bw, c1_sw, c1_sc, c2_bw, c2_sw, c2_sc, W1g, W2g);
    hipLaunchKernelGGL(k_fused, dim3(512), dim3(384), 0, stream,
                       x, W1g, W2g,
                       fc1_w, fc1_b, fc2_w, fc2_b, fc3_w, fc3_b, out);
}

// Round 9
// 39.844 us; speedup vs baseline: 1.5069x; 1.5069x over previous
//
#include <hip/hip_runtime.h>

// ---------------------------------------------------------------------------
// LeNet5-KAN on MI355X.  R9: R7 structure (proven) + fc occupancy fix
// (512 blocks x 2 img) + conv2 dual MFMA accumulator chains.
// MFMA f16 in / f32 accum; avg-pool folded into weights (stride-2 conv6x6).
//
// GEMM view per conv:  out[p][o] = sum_K feat16[elem(p,tap)][k] * W[tap,k][o]
//   K = taps(36) x kpad(16): k0..7 = cubic B-spline bases, k8 = relu, rest 0.
//   A-frag: lane&15 = out px, lane>>4 = k-group (16B ds_read_b128)
//   B-frag: lane&15 = o,     lane>>4 = same k-group (16B global load, L2)
//   C     : col = lane&15 (o), row = (lane>>4)*4 + reg
// A and B use the identical (group,elem)->k map, so the MFMA-internal k
// permutation cancels (sum over k is permutation invariant).
// feat LDS chunks (16B) XOR-swizzled: ch ^= (ch>>3)&7.
// ---------------------------------------------------------------------------

typedef _Float16 f16;
typedef f16 f16x8 __attribute__((ext_vector_type(8)));
typedef float f32x4 __attribute__((ext_vector_type(4)));

#define ONE_SIXTH 0.16666666666666666f

__device__ __forceinline__ void spline9(float v, float* __restrict__ f) {
    float u  = 2.5f * v + 5.5f;
    bool valid = (u >= 0.0f) && (u < 11.0f);
    float fi = floorf(u);
    int   i  = (int)fi;
    float w  = u - fi;
    float omw = 1.0f - w;
    float w2 = w * w, w3 = w2 * w;
    float c0 = omw * omw * omw * ONE_SIXTH;
    float c1 = (3.0f * w3 - 6.0f * w2 + 4.0f) * ONE_SIXTH;
    float c2 = (-3.0f * w3 + 3.0f * w2 + 3.0f * w + 1.0f) * ONE_SIXTH;
    float c3 = w3 * ONE_SIXTH;
    int j0 = i - 3;
#pragma unroll
    for (int j = 0; j < 8; ++j) {
        int d = j - j0;
        float val = (d == 0) ? c0 : (d == 1) ? c1 : (d == 2) ? c2 : (d == 3) ? c3 : 0.0f;
        f[j] = valid ? val : 0.0f;
    }
    f[8] = fmaxf(v, 0.0f);
}

// two 16B chunks: c0 = bases[0..7] as f16, c1 = {relu, 0 x7}
__device__ __forceinline__ void spline_chunks(float v, uint4& u0, uint4& u1) {
    float f[9];
    spline9(v, f);
    union { f16 h[8]; uint4 u; } a, b;
#pragma unroll
    for (int j = 0; j < 8; ++j) a.h[j] = (f16)f[j];
    b.u.x = 0u; b.u.y = 0u; b.u.z = 0u; b.u.w = 0u;
    b.h[0] = (f16)f[8];
    u0 = a.u; u1 = b.u;
}

// ---------------------------------------------------------------------------
// K0: build pooled-conv weights, f16.
// W1g[(tap*16 + o)*16 + k], tap<36, o<16 (6 valid), k<16 (9 valid)
// W2g[((c*36 + tap)*16 + o)*16 + k], c<6
// w'[ey][ex] = 0.25 * sum_{a,b in {0,1}, 0<=ey-a<5, 0<=ex-b<5} w[ey-a][ex-b]
// ---------------------------------------------------------------------------
__global__ __launch_bounds__(256) void k_prep(
    const float* __restrict__ c1_bw, const float* __restrict__ c1_sw,
    const float* __restrict__ c1_sc,
    const float* __restrict__ c2_bw, const float* __restrict__ c2_sw,
    const float* __restrict__ c2_sc,
    f16* __restrict__ W1g, f16* __restrict__ W2g)
{
    int t = blockIdx.x * 256 + threadIdx.x;
    if (t < 9216) {
        int tap = t >> 8, r = t & 255;
        int o = r >> 4, k = r & 15;
        float val = 0.0f;
        if (o < 6 && k < 9) {
            int ey = tap / 6, ex = tap - 6 * ey;
            float s = 0.0f;
            for (int a = 0; a < 2; ++a) {
                for (int b = 0; b < 2; ++b) {
                    int dy = ey - a, dx = ex - b;
                    if (dy >= 0 && dy < 5 && dx >= 0 && dx < 5) {
                        int idx = o * 25 + dy * 5 + dx;
                        s += (k == 8) ? c1_bw[idx] : c1_sw[idx * 8 + k] * c1_sc[idx];
                    }
                }
            }
            val = 0.25f * s;
        }
        W1g[t] = (f16)val;
    }
    if (t < 55296) {
        int c = t / 9216, r = t - c * 9216;
        int tap = r >> 8, rr = r & 255;
        int o = rr >> 4, k = rr & 15;
        float val = 0.0f;
        if (k < 9) {
            int ey = tap / 6, ex = tap - 6 * ey;
            float s = 0.0f;
            for (int a = 0; a < 2; ++a) {
                for (int b = 0; b < 2; ++b) {
                    int dy = ey - a, dx = ex - b;
                    if (dy >= 0 && dy < 5 && dx >= 0 && dx < 5) {
                        int idx = o * 150 + c * 25 + dy * 5 + dx;
                        s += (k == 8) ? c2_bw[idx] : c2_sw[idx * 8 + k] * c2_sc[idx];
                    }
                }
            }
            val = 0.25f * s;
        }
        W2g[t] = (f16)val;
    }
}

// ---------------------------------------------------------------------------
// K1: fused conv1+pool -> conv2+pool. One block = 1 image, 192 thr = 3 waves.
// Phase A: spline-stage x (784 elems) into feat LDS.
// Phase B: conv1 MFMA (3 waves x 3 M-tiles x 18 kc); C-frags -> h1 in LDS.
// Phase C: spline-stage h1 (864 elems) into feat LDS (re-aliased).
// Phase D: conv2 MFMA, K split 3 ways, dual acc chains; LDS reduce -> h2.
// ---------------------------------------------------------------------------
__global__ __launch_bounds__(192, 3) void k_conv12(
    const float* __restrict__ x, const f16* __restrict__ W1g,
    const f16* __restrict__ W2g, float* __restrict__ h2)
{
    __shared__ uint4  feat[1728];    // A: 1568 used; C: 1728 used (aliased)
    __shared__ float  h1l[864];      // conv1 output [o][144] f32
    __shared__ float4 rbuf[2][64];   // conv2 partial sums (waves 1,2)

    const int img = blockIdx.x;
    const int tid = threadIdx.x;
    const int lane = tid & 63, wv = tid >> 6;
    const int ln15 = lane & 15, g = lane >> 4;
    const int gh = g & 1, gt = g >> 1;

    // ---- Phase A: stage feat(x) ----
    for (int e = tid; e < 784; e += 192) {
        uint4 u0, u1;
        spline_chunks(x[img * 784 + e], u0, u1);
        int ch = e * 2;
        int q = (ch >> 3) & 7;
        feat[ch ^ q] = u0;
        feat[(ch + 1) ^ q] = u1;
    }
    __syncthreads();

    // ---- Phase B: conv1 ----
    {
        int ebase[3];
#pragma unroll
        for (int t = 0; t < 3; ++t) {
            int p = (wv * 3 + t) * 16 + ln15;
            int py = p / 12, px = p - py * 12;
            ebase[t] = py * 56 + px * 2;            // (2py)*28 + 2px
        }
        const f16* bptr = W1g + (gt * 16 + ln15) * 16 + gh * 8;
        f16x8 bfrag = *(const f16x8*)bptr;
        f32x4 acc[3] = {{0,0,0,0},{0,0,0,0},{0,0,0,0}};

        for (int kc = 0; kc < 18; ++kc) {
            int tap = kc * 2 + gt;
            int ey = (tap * 171) >> 10, ex = tap - ey * 6;
            int eoff = ey * 28 + ex;
            f16x8 bcur = bfrag;
            bptr += 512;
            bfrag = *(const f16x8*)bptr;            // overreads into W2g: safe
#pragma unroll
            for (int t = 0; t < 3; ++t) {
                int ch = (ebase[t] + eoff) * 2 + gh;
                ch ^= (ch >> 3) & 7;
                f16x8 afrag = *(const f16x8*)(&feat[ch]);
                acc[t] = __builtin_amdgcn_mfma_f32_16x16x32_f16(afrag, bcur, acc[t], 0, 0, 0);
            }
        }
        if (ln15 < 6) {
#pragma unroll
            for (int t = 0; t < 3; ++t) {
                int p0 = (wv * 3 + t) * 16 + g * 4;     // row = g*4 + reg
                *(float4*)&h1l[ln15 * 144 + p0] =
                    make_float4(acc[t][0], acc[t][1], acc[t][2], acc[t][3]);
            }
        }
    }
    __syncthreads();    // feat reads done + h1l visible

    // ---- Phase C: stage feat(h1) ----
    for (int e = tid; e < 864; e += 192) {
        uint4 u0, u1;
        spline_chunks(h1l[e], u0, u1);
        int ch = e * 2;
        int q = (ch >> 3) & 7;
        feat[ch ^ q] = u0;
        feat[(ch + 1) ^ q] = u1;
    }
    __syncthreads();

    // ---- Phase D: conv2, K split over 3 waves, dual acc chains ----
    {
        const int py = ln15 >> 2, px = ln15 & 3;
        const int epx = py * 24 + px * 2;           // (2py)*12 + 2px
        const int kk0 = wv * 36;
        const f16* bptr = W2g + ((kk0 * 2 + gt) * 16 + ln15) * 16 + gh * 8;
        f16x8 bfrag = *(const f16x8*)bptr;
        f32x4 accA = {0, 0, 0, 0}, accB = {0, 0, 0, 0};

        for (int i = 0; i < 36; i += 2) {
#pragma unroll
            for (int s = 0; s < 2; ++s) {
                int kk = kk0 + i + s;
                int c = kk / 18, tk = kk - c * 18;
                int tap = tk * 2 + gt;
                int ey = (tap * 171) >> 10, ex = tap - ey * 6;
                f16x8 bcur = bfrag;
                bptr += 512;
                bfrag = *(const f16x8*)bptr;        // overread past W2g: padded
                int elem = c * 144 + epx + ey * 12 + ex;
                int ch = elem * 2 + gh;
                ch ^= (ch >> 3) & 7;
                f16x8 afrag = *(const f16x8*)(&feat[ch]);
                if (s == 0)
                    accA = __builtin_amdgcn_mfma_f32_16x16x32_f16(afrag, bcur, accA, 0, 0, 0);
                else
                    accB = __builtin_amdgcn_mfma_f32_16x16x32_f16(afrag, bcur, accB, 0, 0, 0);
            }
        }
        f32x4 acc = accA + accB;

        if (wv) rbuf[wv - 1][lane] = make_float4(acc[0], acc[1], acc[2], acc[3]);
        __syncthreads();
        if (wv == 0) {
            float4 r0 = rbuf[0][lane], r1 = rbuf[1][lane];
            *(float4*)&h2[img * 256 + ln15 * 16 + g * 4] =
                make_float4(acc[0] + r0.x + r1.x, acc[1] + r0.y + r1.y,
                            acc[2] + r0.z + r1.z, acc[3] + r0.w + r1.w);
        }
    }
}

// ---------------------------------------------------------------------------
// K3: fc1(relu) -> fc2(relu) -> fc3. Block = 2 batch rows, 256 threads,
// 512 blocks (2/CU). Weight rows L2-resident (183 KB total).
// ---------------------------------------------------------------------------
__global__ __launch_bounds__(256) void k_fc(
    const float* __restrict__ h2,
    const float* __restrict__ w1, const float* __restrict__ b1,
    const float* __restrict__ w2, const float* __restrict__ b2,
    const float* __restrict__ w3, const float* __restrict__ b3,
    float* __restrict__ out)
{
    __shared__ float xin[2][260];
    __shared__ float a1[2][120];
    __shared__ float a2[2][84];
    const int tid = threadIdx.x;
    const int r0 = blockIdx.x * 2;

    for (int i = tid; i < 512; i += 256)
        xin[i >> 8][i & 255] = h2[r0 * 256 + i];
    __syncthreads();

    if (tid < 240) {                  // 120 out x 2 rows
        const int o = tid >> 1, r = tid & 1;
        const float* w = w1 + o * 256;
        float s = 0.0f;
#pragma unroll 8
        for (int k = 0; k < 64; ++k) {
            float4 wv = ((const float4*)w)[k];
            float4 xv = *(const float4*)(&xin[r][k * 4]);
            s += wv.x * xv.x + wv.y * xv.y + wv.z * xv.z + wv.w * xv.w;
        }
        a1[r][o] = fmaxf(s + b1[o], 0.0f);
    }
    __syncthreads();

    if (tid < 168) {                  // 84 out x 2 rows
        const int o = tid >> 1, r = tid & 1;
        const float* w = w2 + o * 120;
        float s = 0.0f;
#pragma unroll
        for (int k = 0; k < 30; ++k) {
            float4 wv = ((const float4*)w)[k];
            float4 xv = *(const float4*)(&a1[r][k * 4]);
            s += wv.x * xv.x + wv.y * xv.y + wv.z * xv.z + wv.w * xv.w;
        }
        a2[r][o] = fmaxf(s + b2[o], 0.0f);
    }
    __syncthreads();

    if (tid < 124) {                  // 62 out x 2 rows
        const int o = tid >> 1, r = tid & 1;
        const float* w = w3 + o * 84;
        float s = 0.0f;
#pragma unroll
        for (int k = 0; k < 21; ++k) {
            float4 wv = ((const float4*)w)[k];
            float4 xv = *(const float4*)(&a2[r][k * 4]);
            s += wv.x * xv.x + wv.y * xv.y + wv.z * xv.z + wv.w * xv.w;
        }
        out[(r0 + r) * 62 + o] = s + b3[o];
    }
}

// ---------------------------------------------------------------------------
extern "C" void kernel_launch(void* const* d_in, const int* in_sizes, int n_in,
                              void* d_out, int out_size, void* d_ws, size_t ws_size,
                              hipStream_t stream)
{
    (void)in_sizes; (void)n_in; (void)out_size; (void)ws_size;
    const float* x      = (const float*)d_in[0];
    const float* c1_bw  = (const float*)d_in[1];
    const float* c1_sw  = (const float*)d_in[2];
    const float* c1_sc  = (const float*)d_in[3];
    const float* c2_bw  = (const float*)d_in[4];
    const float* c2_sw  = (const float*)d_in[5];
    const float* c2_sc  = (const float*)d_in[6];
    const float* fc1_w  = (const float*)d_in[7];
    const float* fc1_b  = (const float*)d_in[8];
    const float* fc2_w  = (const float*)d_in[9];
    const float* fc2_b  = (const float*)d_in[10];
    const float* fc3_w  = (const float*)d_in[11];
    const float* fc3_b  = (const float*)d_in[12];
    float* out = (float*)d_out;

    char* wsb = (char*)d_ws;
    f16*   W1g = (f16*)(wsb);                  //  9216 f16 = 18432 B
    f16*   W2g = (f16*)(wsb + 18432);          // 55296 f16 = 110592 B (+pad)
    float* h2  = (float*)(wsb + 131072);       // 1024*256 f32

    hipLaunchKernelGGL(k_prep, dim3(256), dim3(256), 0, stream,
                       c1_bw, c1_sw, c1_sc, c2_bw, c2_sw, c2_sc, W1g, W2g);
    hipLaunchKernelGGL(k_conv12, dim3(1024), dim3(192), 0, stream,
                       x, W1g, W2g, h2);
    hipLaunchKernelGGL(k_fc, dim3(512), dim3(256), 0, stream,
                       h2, fc1_w, fc1_b, fc2_w, fc2_b, fc3_w, fc3_b, out);
}